// Round 1
// baseline (2423.750 us; speedup 1.0000x reference)
//
#include <hip/hip_runtime.h>
#include <hip/hip_bf16.h>

#define B_ 2
#define CIN 128
#define HIN 91
#define WIN 180
#define NIN (HIN*WIN)         // 16380
#define COUT_ 64
#define HOUT 181
#define WOUT 360
#define NOUT (HOUT*WOUT)      // 65160
#define KK 9
#define NNZ_ (NOUT*8)         // 521280
#define CTOT 128
#define NH 4
#define HD 32
#define EPS_ 1e-5f

// workspace layout (float offsets)
#define OFF_XW ((size_t)0)                           // xw [B][K][NIN][64], later reused as o [B][NOUT][128]
#define OFF_H  ((size_t)B_*KK*NIN*COUT_)             // 18869760 : h [B][NOUT][128] channel-last
#define OFF_S1 (OFF_H + (size_t)B_*NOUT*CTOT)        // 32 floats: GN1 sums
#define OFF_S2 (OFF_S1 + 32)                         // 32 floats: GN2 sums
#define OFF_WT (OFF_S2 + 32)                         // wt [K][CIN][COUT]

// ---------------- w_disco transpose: wt[k][cin][cout] = wd[cout][cin][k] ----------------
__global__ __launch_bounds__(256) void kT(const float* __restrict__ wd, float* __restrict__ wt) {
    int idx = blockIdx.x * 256 + threadIdx.x;
    if (idx >= KK * CIN * COUT_) return;
    int cout = idx & 63;
    int rest = idx >> 6;
    int cin = rest & 127;
    int k = rest >> 7;
    wt[idx] = wd[((size_t)cout * CIN + cin) * KK + k];
}

// ---------------- xw[b][k][n][cout] = quad[n/WIN] * sum_cin x[b][cin][n] * wt[k][cin][cout] ----
__global__ __launch_bounds__(256) void kA(const float* __restrict__ x, const float* __restrict__ wt,
                                          const float* __restrict__ quad, float* __restrict__ xw) {
    __shared__ float As[8][128];
    __shared__ float Bs[8][64];
    int n0 = blockIdx.x * 128;
    int k = blockIdx.y;
    int b = blockIdx.z;
    int tid = threadIdx.x;
    int tc = tid & 15;    // 16 groups of 4 couts
    int tp = tid >> 4;    // 16 groups of 8 points
    float acc[8][4];
    #pragma unroll
    for (int i = 0; i < 8; ++i)
        #pragma unroll
        for (int j = 0; j < 4; ++j) acc[i][j] = 0.f;
    const float* xb = x + (size_t)b * CIN * NIN;
    const float* wk = wt + (size_t)k * CIN * COUT_;
    for (int c0 = 0; c0 < CIN; c0 += 8) {
        for (int i = tid; i < 1024; i += 256) {
            int r = i >> 7, nn = i & 127;
            int n = n0 + nn;
            As[r][nn] = (n < NIN) ? xb[(size_t)(c0 + r) * NIN + n] : 0.f;
        }
        for (int i = tid; i < 512; i += 256) {
            int r = i >> 6, cc = i & 63;
            Bs[r][cc] = wk[(size_t)(c0 + r) * COUT_ + cc];
        }
        __syncthreads();
        #pragma unroll
        for (int r = 0; r < 8; ++r) {
            float bv[4];
            #pragma unroll
            for (int j = 0; j < 4; ++j) bv[j] = Bs[r][tc * 4 + j];
            #pragma unroll
            for (int i = 0; i < 8; ++i) {
                float av = As[r][tp * 8 + i];
                #pragma unroll
                for (int j = 0; j < 4; ++j) acc[i][j] += av * bv[j];
            }
        }
        __syncthreads();
    }
    #pragma unroll
    for (int i = 0; i < 8; ++i) {
        int n = n0 + tp * 8 + i;
        if (n >= NIN) continue;
        float qd = quad[n / WIN];
        float* dst = xw + (((size_t)(b * KK + k) * NIN + n) << 6) + tc * 4;
        #pragma unroll
        for (int j = 0; j < 4; ++j) dst[j] = acc[i][j] * qd;
    }
}

// ---------------- sparse scatter: h[b][row][cout] += psi * xw[b][ker][col][cout] -------------
__global__ __launch_bounds__(256) void kScatter(const float* __restrict__ xw, const float* __restrict__ psi,
                                                const int* __restrict__ row, const int* __restrict__ col,
                                                const int* __restrict__ ker, float* __restrict__ h) {
    int lane = threadIdx.x & 63;
    int wid = threadIdx.x >> 6;
    int b = blockIdx.y;
    int e0 = (blockIdx.x * 4 + wid) * 8;
    #pragma unroll 2
    for (int i = 0; i < 8; ++i) {
        int e = e0 + i;
        if (e >= NNZ_) break;
        int r = row[e], c = col[e], kk = ker[e];
        float p = psi[e];
        float v = p * xw[(((size_t)(b * KK + kk) * NIN + c) << 6) + lane];
        atomicAdd(&h[(((size_t)b * NOUT + r) << 7) + lane], v);
    }
}

// ---------------- skip transpose into h channels 64..127 -------------------------------------
__global__ __launch_bounds__(256) void kSkip(const float* __restrict__ skip, float* __restrict__ h) {
    __shared__ float tile[32][33];
    int n0 = blockIdx.x * 32, c0 = blockIdx.y * 32, b = blockIdx.z;
    int tx = threadIdx.x, ty = threadIdx.y;
    #pragma unroll
    for (int j = 0; j < 4; ++j) {
        int c = c0 + ty + j * 8, n = n0 + tx;
        if (n < NOUT) tile[ty + j * 8][tx] = skip[((size_t)b * 64 + c) * NOUT + n];
    }
    __syncthreads();
    #pragma unroll
    for (int j = 0; j < 4; ++j) {
        int n = n0 + ty + j * 8, c = c0 + tx;
        if (n < NOUT) h[(((size_t)b * NOUT + n) << 7) + 64 + c] = tile[tx][ty + j * 8];
    }
}

// ---------------- GN1 stats: sum,sumsq over (8 ch x NOUT) per (b,g), y includes b_disco ------
__global__ __launch_bounds__(256) void kStats1(const float* __restrict__ h, const float* __restrict__ bd,
                                               float* __restrict__ s1) {
    int bg = blockIdx.y;
    int b = bg >> 3, g = bg & 7;
    float s = 0.f, sq = 0.f;
    const int total = NOUT * 2;  // float4 count
    for (int idx = blockIdx.x * 256 + threadIdx.x; idx < total; idx += 64 * 256) {
        int n = idx >> 1, c4 = idx & 1;
        const float4 v = *reinterpret_cast<const float4*>(h + (((size_t)b * NOUT + n) << 7) + g * 8 + c4 * 4);
        const float4 b4 = *reinterpret_cast<const float4*>(bd + g * 8 + c4 * 4);
        float a0 = v.x + b4.x, a1 = v.y + b4.y, a2 = v.z + b4.z, a3 = v.w + b4.w;
        s += a0 + a1 + a2 + a3;
        sq += a0 * a0 + a1 * a1 + a2 * a2 + a3 * a3;
    }
    for (int o = 32; o; o >>= 1) { s += __shfl_down(s, o); sq += __shfl_down(sq, o); }
    __shared__ float red[8];
    int wv = threadIdx.x >> 6;
    if ((threadIdx.x & 63) == 0) { red[wv * 2] = s; red[wv * 2 + 1] = sq; }
    __syncthreads();
    if (threadIdx.x == 0) {
        float S = 0.f, SQ = 0.f;
        for (int w = 0; w < 4; ++w) { S += red[w * 2]; SQ += red[w * 2 + 1]; }
        atomicAdd(&s1[bg * 2], S);
        atomicAdd(&s1[bg * 2 + 1], SQ);
    }
}

// ---------------- apply GN1 + exact GELU in place on h channels 0..63 ------------------------
__global__ __launch_bounds__(256) void kApply1(float* __restrict__ h, const float* __restrict__ bd,
                                               const float* __restrict__ g1, const float* __restrict__ b1,
                                               const float* __restrict__ s1) {
    size_t idx = (size_t)blockIdx.x * 256 + threadIdx.x;
    if (idx >= (size_t)B_ * NOUT * 16) return;
    int c4 = (int)(idx & 15);
    size_t pn = idx >> 4;
    int b = pn >= (size_t)NOUT;
    int g = c4 >> 1;
    const float invc = 1.0f / (8.0f * NOUT);
    float mu = s1[(b * 8 + g) * 2] * invc;
    float ex2 = s1[(b * 8 + g) * 2 + 1] * invc;
    float rstd = rsqrtf(ex2 - mu * mu + EPS_);
    float* p = h + (pn << 7) + (c4 << 2);
    float4 v = *reinterpret_cast<float4*>(p);
    float r[4] = {v.x, v.y, v.z, v.w};
    #pragma unroll
    for (int j = 0; j < 4; ++j) {
        int c = (c4 << 2) + j;
        float a = r[j] + bd[c];
        float t = (a - mu) * rstd * g1[c] + b1[c];
        r[j] = t * 0.5f * (1.0f + erff(t * 0.70710678118654752f));
    }
    v.x = r[0]; v.y = r[1]; v.z = r[2]; v.w = r[3];
    *reinterpret_cast<float4*>(p) = v;
}

// ---------------- GN2 stats over all 128 channels (16/group) ---------------------------------
__global__ __launch_bounds__(256) void kStats2(const float* __restrict__ h, float* __restrict__ s2) {
    int bg = blockIdx.y;
    int b = bg >> 3, g = bg & 7;
    float s = 0.f, sq = 0.f;
    const int total = NOUT * 4;  // float4 count
    for (int idx = blockIdx.x * 256 + threadIdx.x; idx < total; idx += 64 * 256) {
        int n = idx >> 2, c4 = idx & 3;
        const float4 v = *reinterpret_cast<const float4*>(h + (((size_t)b * NOUT + n) << 7) + g * 16 + c4 * 4);
        s += v.x + v.y + v.z + v.w;
        sq += v.x * v.x + v.y * v.y + v.z * v.z + v.w * v.w;
    }
    for (int o = 32; o; o >>= 1) { s += __shfl_down(s, o); sq += __shfl_down(sq, o); }
    __shared__ float red[8];
    int wv = threadIdx.x >> 6;
    if ((threadIdx.x & 63) == 0) { red[wv * 2] = s; red[wv * 2 + 1] = sq; }
    __syncthreads();
    if (threadIdx.x == 0) {
        float S = 0.f, SQ = 0.f;
        for (int w = 0; w < 4; ++w) { S += red[w * 2]; SQ += red[w * 2 + 1]; }
        atomicAdd(&s2[bg * 2], S);
        atomicAdd(&s2[bg * 2 + 1], SQ);
    }
}

// ---------------- fused ring attention: per (head, ring, b) ----------------------------------
// t = GN2(h) staged bf16 in LDS; k,v bf16 in LDS; per-query online softmax; writes o slice.
__global__ __launch_bounds__(384) void kRing(const float* __restrict__ h, const float* __restrict__ wqkv,
                                             const float* __restrict__ bqkv, const float* __restrict__ g2,
                                             const float* __restrict__ b2, const float* __restrict__ s2,
                                             float* __restrict__ o) {
    __shared__ __hip_bfloat16 t_sm[360][130];   // pad 130: (w + c/2) % 32 banks -> conflict-free row reads
    __shared__ __hip_bfloat16 k_sm[360][32];
    __shared__ __hip_bfloat16 v_sm[360][32];
    __shared__ __hip_bfloat16 w_smT[64][132];   // [col][cin], pad 132
    int head = blockIdx.x, ring = blockIdx.y, b = blockIdx.z;
    int tid = threadIdx.x;
    const float* hb = h + (((size_t)b * NOUT + (size_t)ring * 360) << 7);
    const float invc2 = 1.0f / (16.0f * NOUT);

    // phase 1: stage normalized t (bf16)
    for (int idx = tid; idx < 360 * 32; idx += 384) {
        int w = idx >> 5, c4 = idx & 31;
        int c = c4 * 4;
        int g = c >> 4;
        float mu = s2[(b * 8 + g) * 2] * invc2;
        float rstd = rsqrtf(s2[(b * 8 + g) * 2 + 1] * invc2 - mu * mu + EPS_);
        float4 v = *reinterpret_cast<const float4*>(hb + ((size_t)w << 7) + c);
        t_sm[w][c + 0] = __float2bfloat16((v.x - mu) * rstd * g2[c + 0] + b2[c + 0]);
        t_sm[w][c + 1] = __float2bfloat16((v.y - mu) * rstd * g2[c + 1] + b2[c + 1]);
        t_sm[w][c + 2] = __float2bfloat16((v.z - mu) * rstd * g2[c + 2] + b2[c + 2]);
        t_sm[w][c + 3] = __float2bfloat16((v.w - mu) * rstd * g2[c + 3] + b2[c + 3]);
    }
    // stage k/v weight slices: w_smT[j][c], j<32 -> k col, j>=32 -> v col
    for (int idx = tid; idx < 8192; idx += 384) {
        int c = idx >> 6, j = idx & 63;
        int col = (j < 32) ? (CTOT + head * HD + j) : (2 * CTOT + head * HD + (j - 32));
        w_smT[j][c] = __float2bfloat16(wqkv[(size_t)c * 384 + col]);
    }
    __syncthreads();

    // phase 2: k, v into LDS
    {
        int d = tid & 31, wsub = tid >> 5;  // wsub 0..11
        float bk = bqkv[CTOT + head * HD + d];
        float bv = bqkv[2 * CTOT + head * HD + d];
        for (int pass = 0; pass < 30; ++pass) {
            int wk = pass * 12 + wsub;
            float ak = bk, av = bv;
            #pragma unroll 8
            for (int c = 0; c < 128; c += 2) {
                float2 tv = __bfloat1622float2(*reinterpret_cast<const __hip_bfloat162*>(&t_sm[wk][c]));
                float2 wkk = __bfloat1622float2(*reinterpret_cast<const __hip_bfloat162*>(&w_smT[d][c]));
                float2 wvv = __bfloat1622float2(*reinterpret_cast<const __hip_bfloat162*>(&w_smT[32 + d][c]));
                ak += tv.x * wkk.x + tv.y * wkk.y;
                av += tv.x * wvv.x + tv.y * wvv.y;
            }
            k_sm[wk][d] = __float2bfloat16(ak);
            v_sm[wk][d] = __float2bfloat16(av);
        }
    }
    __syncthreads();
    // restage q weights into w_smT rows 0..31
    for (int idx = tid; idx < 4096; idx += 384) {
        int c = idx >> 5, d = idx & 31;
        w_smT[d][c] = __float2bfloat16(wqkv[(size_t)c * 384 + head * HD + d]);
    }
    __syncthreads();

    // phase 3: per-query online-softmax attention
    if (tid < 360) {
        int w = tid;
        float q[32];
        #pragma unroll
        for (int d = 0; d < 32; ++d) q[d] = bqkv[head * HD + d];
        for (int c = 0; c < 128; c += 2) {
            float2 tv = __bfloat1622float2(*reinterpret_cast<const __hip_bfloat162*>(&t_sm[w][c]));
            #pragma unroll
            for (int d = 0; d < 32; ++d) {
                float2 wq = __bfloat1622float2(*reinterpret_cast<const __hip_bfloat162*>(&w_smT[d][c]));
                q[d] += tv.x * wq.x + tv.y * wq.y;
            }
        }
        const float scale = 0.17677669529663688f;  // 1/sqrt(32)
        #pragma unroll
        for (int d = 0; d < 32; ++d) q[d] *= scale;
        float m = -INFINITY, l = 0.f;
        float acc[32];
        #pragma unroll
        for (int d = 0; d < 32; ++d) acc[d] = 0.f;
        for (int wk = 0; wk < 360; ++wk) {
            const __hip_bfloat162* kr = reinterpret_cast<const __hip_bfloat162*>(&k_sm[wk][0]);
            float s = 0.f;
            #pragma unroll
            for (int d2 = 0; d2 < 16; ++d2) {
                float2 kf = __bfloat1622float2(kr[d2]);
                s += q[2 * d2] * kf.x + q[2 * d2 + 1] * kf.y;
            }
            float mn = fmaxf(m, s);
            float corr = __expf(m - mn);
            float p = __expf(s - mn);
            l = l * corr + p;
            const __hip_bfloat162* vr = reinterpret_cast<const __hip_bfloat162*>(&v_sm[wk][0]);
            #pragma unroll
            for (int d2 = 0; d2 < 16; ++d2) {
                float2 vf = __bfloat1622float2(vr[d2]);
                acc[2 * d2] = acc[2 * d2] * corr + p * vf.x;
                acc[2 * d2 + 1] = acc[2 * d2 + 1] * corr + p * vf.y;
            }
            m = mn;
        }
        float inv_l = 1.f / l;
        float* dst = o + (((size_t)b * NOUT + (size_t)ring * 360 + w) << 7) + head * HD;
        #pragma unroll
        for (int d2 = 0; d2 < 8; ++d2) {
            float4 ov;
            ov.x = acc[4 * d2 + 0] * inv_l;
            ov.y = acc[4 * d2 + 1] * inv_l;
            ov.z = acc[4 * d2 + 2] * inv_l;
            ov.w = acc[4 * d2 + 3] * inv_l;
            *reinterpret_cast<float4*>(dst + 4 * d2) = ov;
        }
    }
}

// ---------------- final: out[b][c][n] = (o @ wo)[n][c] + bo[c] + h[b][n][c] ------------------
__global__ __launch_bounds__(256) void kFinal(const float* __restrict__ o, const float* __restrict__ wo,
                                              const float* __restrict__ bo, const float* __restrict__ h,
                                              float* __restrict__ out) {
    __shared__ float o_sm[64][16];
    __shared__ float w_sm2[16][128];
    __shared__ float tr[128][65];
    size_t p0 = (size_t)blockIdx.x * 64;
    int tid = threadIdx.x;
    int tc = tid & 31, tp = tid >> 5;
    const size_t PTOT = (size_t)B_ * NOUT;
    float acc[8][4];
    #pragma unroll
    for (int i = 0; i < 8; ++i)
        #pragma unroll
        for (int j = 0; j < 4; ++j) acc[i][j] = 0.f;
    for (int c0 = 0; c0 < 128; c0 += 16) {
        for (int i = tid; i < 1024; i += 256) {
            int pp = i >> 4, cc = i & 15;
            size_t p = p0 + pp;
            o_sm[pp][cc] = (p < PTOT) ? o[(p << 7) + c0 + cc] : 0.f;
        }
        for (int i = tid; i < 2048; i += 256) {
            int r = i >> 7, cc = i & 127;
            w_sm2[r][cc] = wo[(size_t)(c0 + r) * 128 + cc];
        }
        __syncthreads();
        #pragma unroll
        for (int r = 0; r < 16; ++r) {
            float bv[4];
            #pragma unroll
            for (int j = 0; j < 4; ++j) bv[j] = w_sm2[r][tc * 4 + j];
            #pragma unroll
            for (int i = 0; i < 8; ++i) {
                float av = o_sm[tp * 8 + i][r];
                #pragma unroll
                for (int j = 0; j < 4; ++j) acc[i][j] += av * bv[j];
            }
        }
        __syncthreads();
    }
    #pragma unroll
    for (int i = 0; i < 8; ++i) {
        size_t p = p0 + tp * 8 + i;
        if (p < PTOT) {
            #pragma unroll
            for (int j = 0; j < 4; ++j) {
                int c = tc * 4 + j;
                tr[c][tp * 8 + i] = acc[i][j] + bo[c] + h[(p << 7) + c];
            }
        } else {
            #pragma unroll
            for (int j = 0; j < 4; ++j) tr[tc * 4 + j][tp * 8 + i] = 0.f;
        }
    }
    __syncthreads();
    for (int pass = 0; pass < 32; ++pass) {
        int idx = pass * 256 + tid;
        int row = idx >> 6, pc = idx & 63;
        size_t p = p0 + pc;
        if (p < PTOT) {
            int b = p >= (size_t)NOUT;
            size_t n = p - (size_t)b * NOUT;
            out[((size_t)(b * 128 + row)) * NOUT + n] = tr[row][pc];
        }
    }
}

extern "C" void kernel_launch(void* const* d_in, const int* in_sizes, int n_in,
                              void* d_out, int out_size, void* d_ws, size_t ws_size,
                              hipStream_t stream) {
    const float* x    = (const float*)d_in[0];
    const float* skip = (const float*)d_in[1];
    const float* wd   = (const float*)d_in[2];
    const float* bd   = (const float*)d_in[3];
    const float* psi  = (const float*)d_in[4];
    const float* quad = (const float*)d_in[5];
    const float* g1   = (const float*)d_in[6];
    const float* b1   = (const float*)d_in[7];
    const float* g2   = (const float*)d_in[8];
    const float* b2   = (const float*)d_in[9];
    const float* wqkv = (const float*)d_in[10];
    const float* bqkv = (const float*)d_in[11];
    const float* wo   = (const float*)d_in[12];
    const float* bo   = (const float*)d_in[13];
    const int* row    = (const int*)d_in[14];
    const int* col    = (const int*)d_in[15];
    const int* ker    = (const int*)d_in[16];
    float* ws = (float*)d_ws;
    float* xw = ws + OFF_XW;   // also o after scatter is done
    float* h  = ws + OFF_H;
    float* s1 = ws + OFF_S1;
    float* s2 = ws + OFF_S2;
    float* wt = ws + OFF_WT;
    float* out = (float*)d_out;

    // zero h + stats (y accumulator must start at 0; stats are atomicAdd targets)
    hipMemsetAsync(h, 0, ((size_t)B_ * NOUT * CTOT + 64) * sizeof(float), stream);

    kT<<<288, 256, 0, stream>>>(wd, wt);
    kA<<<dim3(128, KK, B_), 256, 0, stream>>>(x, wt, quad, xw);
    kScatter<<<dim3(NNZ_ / 32, B_), 256, 0, stream>>>(xw, psi, row, col, ker, h);
    kSkip<<<dim3((NOUT + 31) / 32, 2, B_), dim3(32, 8), 0, stream>>>(skip, h);
    kStats1<<<dim3(64, 16), 256, 0, stream>>>(h, bd, s1);
    kApply1<<<(int)(((size_t)B_ * NOUT * 16 + 255) / 256), 256, 0, stream>>>(h, bd, g1, b1, s1);
    kStats2<<<dim3(64, 16), 256, 0, stream>>>(h, s2);
    kRing<<<dim3(NH, HOUT, B_), 384, 0, stream>>>(h, wqkv, bqkv, g2, b2, s2, xw);
    kFinal<<<(int)(((size_t)B_ * NOUT + 63) / 64), 256, 0, stream>>>(xw, wo, bo, h, out);
}

// Round 2
// 768.610 us; speedup vs baseline: 3.1534x; 3.1534x over previous
//
#include <hip/hip_runtime.h>
#include <hip/hip_bf16.h>

#define B_ 2
#define CIN 128
#define HIN 91
#define WIN 180
#define NIN (HIN*WIN)         // 16380
#define COUT_ 64
#define HOUT 181
#define WOUT 360
#define NOUT (HOUT*WOUT)      // 65160
#define KK 9
#define NNZ_ (NOUT*8)         // 521280
#define CTOT 128
#define NH 4
#define HD 32
#define EPS_ 1e-5f
#define PTOT ((size_t)B_*NOUT)   // 130320

typedef short s16x8 __attribute__((ext_vector_type(8)));
typedef float f32x4v __attribute__((ext_vector_type(4)));
typedef float f32x16v __attribute__((ext_vector_type(16)));
typedef int i32x2v __attribute__((ext_vector_type(2)));

// workspace layout (float offsets)
// phase 1: xw [B][K][NIN][64] f32 occupies [0, 18869760)
// phase 2 (xw dead after scatter): q bf16 + k bf16 overlay the xw region; o (bf16) aliases q.
#define OFF_Q  ((size_t)0)
#define OFF_K  ((size_t)8340480)
#define OFF_H  ((size_t)18869760)
#define OFF_S1 (OFF_H + (size_t)B_*NOUT*CTOT)        // 35550720
#define OFF_S2 (OFF_S1 + 32)
#define OFF_WT (OFF_S2 + 32)                         // 73728 floats
#define OFF_VT (OFF_WT + (size_t)KK*CIN*COUT_)       // 35624512, vt bf16 [B*128][NOUT]

__device__ inline ushort f2b(float x) { return __bfloat16_as_ushort(__float2bfloat16(x)); }
__device__ inline float b2f(ushort u) { return __bfloat162float(__ushort_as_bfloat16(u)); }
__device__ inline uint pk2(float lo, float hi) {
    return (uint)f2b(lo) | ((uint)f2b(hi) << 16);
}

// ---------------- w_disco transpose: wt[k][cin][cout] = wd[cout][cin][k] ----------------
__global__ __launch_bounds__(256) void kT(const float* __restrict__ wd, float* __restrict__ wt) {
    int idx = blockIdx.x * 256 + threadIdx.x;
    if (idx >= KK * CIN * COUT_) return;
    int cout = idx & 63;
    int rest = idx >> 6;
    int cin = rest & 127;
    int k = rest >> 7;
    wt[idx] = wd[((size_t)cout * CIN + cin) * KK + k];
}

// ---------------- xw[b][k][n][cout] = quad[n/WIN] * sum_cin x[b][cin][n] * wt[k][cin][cout] ----
__global__ __launch_bounds__(256) void kA(const float* __restrict__ x, const float* __restrict__ wt,
                                          const float* __restrict__ quad, float* __restrict__ xw) {
    __shared__ float As[8][128];
    __shared__ float Bs[8][64];
    int n0 = blockIdx.x * 128;
    int k = blockIdx.y;
    int b = blockIdx.z;
    int tid = threadIdx.x;
    int tc = tid & 15;
    int tp = tid >> 4;
    float acc[8][4];
    #pragma unroll
    for (int i = 0; i < 8; ++i)
        #pragma unroll
        for (int j = 0; j < 4; ++j) acc[i][j] = 0.f;
    const float* xb = x + (size_t)b * CIN * NIN;
    const float* wk = wt + (size_t)k * CIN * COUT_;
    for (int c0 = 0; c0 < CIN; c0 += 8) {
        for (int i = tid; i < 1024; i += 256) {
            int r = i >> 7, nn = i & 127;
            int n = n0 + nn;
            As[r][nn] = (n < NIN) ? xb[(size_t)(c0 + r) * NIN + n] : 0.f;
        }
        for (int i = tid; i < 512; i += 256) {
            int r = i >> 6, cc = i & 63;
            Bs[r][cc] = wk[(size_t)(c0 + r) * COUT_ + cc];
        }
        __syncthreads();
        #pragma unroll
        for (int r = 0; r < 8; ++r) {
            float bv[4];
            #pragma unroll
            for (int j = 0; j < 4; ++j) bv[j] = Bs[r][tc * 4 + j];
            #pragma unroll
            for (int i = 0; i < 8; ++i) {
                float av = As[r][tp * 8 + i];
                #pragma unroll
                for (int j = 0; j < 4; ++j) acc[i][j] += av * bv[j];
            }
        }
        __syncthreads();
    }
    #pragma unroll
    for (int i = 0; i < 8; ++i) {
        int n = n0 + tp * 8 + i;
        if (n >= NIN) continue;
        float qd = quad[n / WIN];
        float* dst = xw + (((size_t)(b * KK + k) * NIN + n) << 6) + tc * 4;
        #pragma unroll
        for (int j = 0; j < 4; ++j) dst[j] = acc[i][j] * qd;
    }
}

// ---------------- sparse scatter: h[b][row][cout] += psi * xw[b][ker][col][cout] -------------
__global__ __launch_bounds__(256) void kScatter(const float* __restrict__ xw, const float* __restrict__ psi,
                                                const int* __restrict__ row, const int* __restrict__ col,
                                                const int* __restrict__ ker, float* __restrict__ h) {
    int lane = threadIdx.x & 63;
    int wid = threadIdx.x >> 6;
    int b = blockIdx.y;
    int e0 = (blockIdx.x * 4 + wid) * 8;
    #pragma unroll 2
    for (int i = 0; i < 8; ++i) {
        int e = e0 + i;
        if (e >= NNZ_) break;
        int r = row[e], c = col[e], kk = ker[e];
        float p = psi[e];
        float v = p * xw[(((size_t)(b * KK + kk) * NIN + c) << 6) + lane];
        atomicAdd(&h[(((size_t)b * NOUT + r) << 7) + lane], v);
    }
}

// ---------------- skip transpose into h channels 64..127 -------------------------------------
__global__ __launch_bounds__(256) void kSkip(const float* __restrict__ skip, float* __restrict__ h) {
    __shared__ float tile[32][33];
    int n0 = blockIdx.x * 32, c0 = blockIdx.y * 32, b = blockIdx.z;
    int tx = threadIdx.x, ty = threadIdx.y;
    #pragma unroll
    for (int j = 0; j < 4; ++j) {
        int c = c0 + ty + j * 8, n = n0 + tx;
        if (n < NOUT) tile[ty + j * 8][tx] = skip[((size_t)b * 64 + c) * NOUT + n];
    }
    __syncthreads();
    #pragma unroll
    for (int j = 0; j < 4; ++j) {
        int n = n0 + ty + j * 8, c = c0 + tx;
        if (n < NOUT) h[(((size_t)b * NOUT + n) << 7) + 64 + c] = tile[tx][ty + j * 8];
    }
}

// ---------------- GN1 stats ------------------------------------------------------------------
__global__ __launch_bounds__(256) void kStats1(const float* __restrict__ h, const float* __restrict__ bd,
                                               float* __restrict__ s1) {
    int bg = blockIdx.y;
    int b = bg >> 3, g = bg & 7;
    float s = 0.f, sq = 0.f;
    const int total = NOUT * 2;
    for (int idx = blockIdx.x * 256 + threadIdx.x; idx < total; idx += 64 * 256) {
        int n = idx >> 1, c4 = idx & 1;
        const float4 v = *reinterpret_cast<const float4*>(h + (((size_t)b * NOUT + n) << 7) + g * 8 + c4 * 4);
        const float4 b4 = *reinterpret_cast<const float4*>(bd + g * 8 + c4 * 4);
        float a0 = v.x + b4.x, a1 = v.y + b4.y, a2 = v.z + b4.z, a3 = v.w + b4.w;
        s += a0 + a1 + a2 + a3;
        sq += a0 * a0 + a1 * a1 + a2 * a2 + a3 * a3;
    }
    for (int o = 32; o; o >>= 1) { s += __shfl_down(s, o); sq += __shfl_down(sq, o); }
    __shared__ float red[8];
    int wv = threadIdx.x >> 6;
    if ((threadIdx.x & 63) == 0) { red[wv * 2] = s; red[wv * 2 + 1] = sq; }
    __syncthreads();
    if (threadIdx.x == 0) {
        float S = 0.f, SQ = 0.f;
        for (int w = 0; w < 4; ++w) { S += red[w * 2]; SQ += red[w * 2 + 1]; }
        atomicAdd(&s1[bg * 2], S);
        atomicAdd(&s1[bg * 2 + 1], SQ);
    }
}

// ---------------- apply GN1 + exact GELU -----------------------------------------------------
__global__ __launch_bounds__(256) void kApply1(float* __restrict__ h, const float* __restrict__ bd,
                                               const float* __restrict__ g1, const float* __restrict__ b1,
                                               const float* __restrict__ s1) {
    size_t idx = (size_t)blockIdx.x * 256 + threadIdx.x;
    if (idx >= (size_t)B_ * NOUT * 16) return;
    int c4 = (int)(idx & 15);
    size_t pn = idx >> 4;
    int b = pn >= (size_t)NOUT;
    int g = c4 >> 1;
    const float invc = 1.0f / (8.0f * NOUT);
    float mu = s1[(b * 8 + g) * 2] * invc;
    float ex2 = s1[(b * 8 + g) * 2 + 1] * invc;
    float rstd = rsqrtf(ex2 - mu * mu + EPS_);
    float* p = h + (pn << 7) + (c4 << 2);
    float4 v = *reinterpret_cast<float4*>(p);
    float r[4] = {v.x, v.y, v.z, v.w};
    #pragma unroll
    for (int j = 0; j < 4; ++j) {
        int c = (c4 << 2) + j;
        float a = r[j] + bd[c];
        float t = (a - mu) * rstd * g1[c] + b1[c];
        r[j] = t * 0.5f * (1.0f + erff(t * 0.70710678118654752f));
    }
    v.x = r[0]; v.y = r[1]; v.z = r[2]; v.w = r[3];
    *reinterpret_cast<float4*>(p) = v;
}

// ---------------- GN2 stats ------------------------------------------------------------------
__global__ __launch_bounds__(256) void kStats2(const float* __restrict__ h, float* __restrict__ s2) {
    int bg = blockIdx.y;
    int b = bg >> 3, g = bg & 7;
    float s = 0.f, sq = 0.f;
    const int total = NOUT * 4;
    for (int idx = blockIdx.x * 256 + threadIdx.x; idx < total; idx += 64 * 256) {
        int n = idx >> 2, c4 = idx & 3;
        const float4 v = *reinterpret_cast<const float4*>(h + (((size_t)b * NOUT + n) << 7) + g * 16 + c4 * 4);
        s += v.x + v.y + v.z + v.w;
        sq += v.x * v.x + v.y * v.y + v.z * v.z + v.w * v.w;
    }
    for (int o = 32; o; o >>= 1) { s += __shfl_down(s, o); sq += __shfl_down(sq, o); }
    __shared__ float red[8];
    int wv = threadIdx.x >> 6;
    if ((threadIdx.x & 63) == 0) { red[wv * 2] = s; red[wv * 2 + 1] = sq; }
    __syncthreads();
    if (threadIdx.x == 0) {
        float S = 0.f, SQ = 0.f;
        for (int w = 0; w < 4; ++w) { S += red[w * 2]; SQ += red[w * 2 + 1]; }
        atomicAdd(&s2[bg * 2], S);
        atomicAdd(&s2[bg * 2 + 1], SQ);
    }
}

// ---------------- kQKV: t = GN2(h); qkv = t @ wqkv + bqkv via MFMA ---------------------------
// writes q (scaled by 1/sqrt(hd)), k row-major bf16 [row][128]; v transposed [b*128+hd*32+d][NOUT]
__global__ __launch_bounds__(256) void kQKV(const float* __restrict__ h, const float* __restrict__ wqkv,
                                            const float* __restrict__ bqkv, const float* __restrict__ g2,
                                            const float* __restrict__ b2, const float* __restrict__ s2,
                                            ushort* __restrict__ qg, ushort* __restrict__ kg,
                                            ushort* __restrict__ vtg) {
    __shared__ ushort As[64][136];    // [row][k] bf16, row stride 272B (16B aligned)
    __shared__ ushort Bs[128][136];   // [n][k] bf16 (wqkv slice transposed)
    __shared__ float muT[16], rsT[16];
    __shared__ float g2T[128], b2T[128];
    int tid = threadIdx.x;
    size_t r0 = (size_t)blockIdx.x * 64;
    int n0 = blockIdx.y * 128;
    const float invc2 = 1.0f / (16.0f * NOUT);
    if (tid < 16) {
        float mu = s2[tid * 2] * invc2;
        float ex2 = s2[tid * 2 + 1] * invc2;
        muT[tid] = mu;
        rsT[tid] = rsqrtf(ex2 - mu * mu + EPS_);
    }
    if (tid < 128) { g2T[tid] = g2[tid]; b2T[tid] = b2[tid]; }
    __syncthreads();
    // stage A = normalized t rows (bf16)
    for (int i = tid; i < 64 * 32; i += 256) {
        int rl = i >> 5, c4 = (i & 31) * 4;
        size_t rg = r0 + rl;
        uint w0 = 0, w1 = 0;
        if (rg < PTOT) {
            int bg8 = (rg >= (size_t)NOUT) ? 8 : 0;
            int g = bg8 + (c4 >> 4);
            float mu = muT[g], rs = rsT[g];
            float4 v = *reinterpret_cast<const float4*>(h + (rg << 7) + c4);
            float t0 = (v.x - mu) * rs * g2T[c4] + b2T[c4];
            float t1 = (v.y - mu) * rs * g2T[c4 + 1] + b2T[c4 + 1];
            float t2 = (v.z - mu) * rs * g2T[c4 + 2] + b2T[c4 + 2];
            float t3 = (v.w - mu) * rs * g2T[c4 + 3] + b2T[c4 + 3];
            w0 = pk2(t0, t1); w1 = pk2(t2, t3);
        }
        *reinterpret_cast<uint*>(&As[rl][c4]) = w0;
        *reinterpret_cast<uint*>(&As[rl][c4 + 2]) = w1;
    }
    // stage B^T: Bs[n][k] = wqkv[k][n0+n]
    for (int i = tid; i < 128 * 32; i += 256) {
        int kk = i >> 5, n4 = (i & 31) * 4;
        float4 v = *reinterpret_cast<const float4*>(wqkv + (size_t)kk * 384 + n0 + n4);
        Bs[n4][kk] = f2b(v.x); Bs[n4 + 1][kk] = f2b(v.y);
        Bs[n4 + 2][kk] = f2b(v.z); Bs[n4 + 3][kk] = f2b(v.w);
    }
    __syncthreads();
    int w = tid >> 6, lane = tid & 63;
    int l16 = lane & 15, kh = lane >> 4;
    f32x4v acc[8];
    #pragma unroll
    for (int nf = 0; nf < 8; ++nf) { acc[nf][0] = 0; acc[nf][1] = 0; acc[nf][2] = 0; acc[nf][3] = 0; }
    #pragma unroll
    for (int ks = 0; ks < 4; ++ks) {
        int kk0 = ks * 32 + kh * 8;
        s16x8 af = *reinterpret_cast<const s16x8*>(&As[w * 16 + l16][kk0]);
        #pragma unroll
        for (int nf = 0; nf < 8; ++nf) {
            s16x8 bf = *reinterpret_cast<const s16x8*>(&Bs[nf * 16 + l16][kk0]);
            acc[nf] = __builtin_amdgcn_mfma_f32_16x16x32_bf16(af, bf, acc[nf], 0, 0, 0);
        }
    }
    __syncthreads();
    // bounce through LDS (reuse As, row stride 136) for coalesced stores
    const float scale = (n0 == 0) ? 0.17677669529663688f : 1.0f;
    #pragma unroll
    for (int nf = 0; nf < 8; ++nf) {
        int cc = nf * 16 + l16;
        float bias = bqkv[n0 + cc];
        #pragma unroll
        for (int j = 0; j < 4; ++j) {
            int rl = w * 16 + kh * 4 + j;
            As[rl][cc] = f2b((acc[nf][j] + bias) * scale);
        }
    }
    __syncthreads();
    if (n0 < 256) {
        ushort* dst = (n0 == 0) ? qg : kg;
        for (int i = tid; i < 64 * 64; i += 256) {
            int rl = i >> 6, dc = i & 63;
            size_t rg = r0 + rl;
            if (rg < PTOT)
                reinterpret_cast<uint*>(dst)[(rg << 6) + dc] =
                    reinterpret_cast<const uint*>(&As[rl][0])[dc];
        }
    } else {
        for (int i = tid; i < 128 * 64; i += 256) {
            int d128 = i >> 6, rl = i & 63;
            size_t rg = r0 + rl;
            if (rg < PTOT) {
                int b = rg >= (size_t)NOUT;
                size_t n = rg - (size_t)b * NOUT;
                vtg[((size_t)(b * 128 + d128)) * NOUT + n] = As[rl][d128];
            }
        }
    }
}

// ---------------- kAttn: flash attention per (head, ring, b) via MFMA 32x32x16 ---------------
__global__ __launch_bounds__(384) void kAttn(const ushort* __restrict__ qg, const ushort* __restrict__ kg,
                                             const ushort* __restrict__ vtg, ushort* __restrict__ og) {
    __shared__ ushort K_sm[384][40];   // [key][d], stride 80B
    __shared__ ushort V_sm[32][392];   // [d][key], stride 784B
    int head = blockIdx.x, ring = blockIdx.y, b = blockIdx.z;
    int tid = threadIdx.x;
    size_t rowbase = (size_t)b * NOUT + (size_t)ring * 360;
    // stage K (rows >=360 zeroed)
    for (int i = tid; i < 1536; i += 384) {
        int r = i >> 2, c = (i & 3) * 8;
        uint4 val = {0, 0, 0, 0};
        if (r < 360) val = *reinterpret_cast<const uint4*>(kg + (rowbase + r) * 128 + head * 32 + c);
        *reinterpret_cast<uint4*>(&K_sm[r][c]) = val;
    }
    // stage V^T (cols >=360 zeroed)
    {
        int d = tid / 12, j = tid % 12;
        const ushort* vp = vtg + ((size_t)(b * 128 + head * 32 + d)) * NOUT + (size_t)ring * 360;
        for (int c8 = j; c8 < 49; c8 += 12) {
            uint4 val = {0, 0, 0, 0};
            if (c8 < 45) val = *reinterpret_cast<const uint4*>(vp + c8 * 8);
            *reinterpret_cast<uint4*>(&V_sm[d][c8 * 8]) = val;
        }
    }
    __syncthreads();
    int wv = tid >> 6, lane = tid & 63;
    int lq = lane & 31, hi = lane >> 5;
    for (int qi = 0; qi < 2; ++qi) {
        int qt = wv + qi * 6;
        int qv = qt * 32 + lq;
        bool qok = qv < 360;
        uint4 qf1 = {0, 0, 0, 0}, qf2 = {0, 0, 0, 0};
        if (qok) {
            const ushort* qp = qg + (rowbase + qv) * 128 + head * 32;
            qf1 = *reinterpret_cast<const uint4*>(qp + hi * 8);
            qf2 = *reinterpret_cast<const uint4*>(qp + 16 + hi * 8);
        }
        s16x8 qa = __builtin_bit_cast(s16x8, qf1);
        s16x8 qb = __builtin_bit_cast(s16x8, qf2);
        f32x16v O;
        #pragma unroll
        for (int r2 = 0; r2 < 16; ++r2) O[r2] = 0.f;
        float m = -INFINITY, lsum = 0.f;
        for (int kt = 0; kt < 12; ++kt) {
            s16x8 ka = *reinterpret_cast<const s16x8*>(&K_sm[kt * 32 + lq][hi * 8]);
            s16x8 kb = *reinterpret_cast<const s16x8*>(&K_sm[kt * 32 + lq][16 + hi * 8]);
            f32x16v S;
            #pragma unroll
            for (int r2 = 0; r2 < 16; ++r2) S[r2] = 0.f;
            S = __builtin_amdgcn_mfma_f32_32x32x16_bf16(ka, qa, S, 0, 0, 0);
            S = __builtin_amdgcn_mfma_f32_32x32x16_bf16(kb, qb, S, 0, 0, 0);
            if (kt == 11) {   // keys 352+row: regs 4..15 are keys >=360 -> mask (uniform!)
                #pragma unroll
                for (int r2 = 4; r2 < 16; ++r2) S[r2] = -1e30f;
            }
            float tm = S[0];
            #pragma unroll
            for (int r2 = 1; r2 < 16; ++r2) tm = fmaxf(tm, S[r2]);
            i32x2v sw = __builtin_amdgcn_permlane32_swap(__float_as_int(tm), __float_as_int(tm), false, false);
            tm = fmaxf(__int_as_float(sw[0]), __int_as_float(sw[1]));
            float mn = fmaxf(m, tm);
            float corr = __expf(m - mn);
            float ps = 0.f;
            #pragma unroll
            for (int r2 = 0; r2 < 16; ++r2) { S[r2] = __expf(S[r2] - mn); ps += S[r2]; }
            sw = __builtin_amdgcn_permlane32_swap(__float_as_int(ps), __float_as_int(ps), false, false);
            ps = __int_as_float(sw[0]) + __int_as_float(sw[1]);
            lsum = lsum * corr + ps;
            m = mn;
            #pragma unroll
            for (int r2 = 0; r2 < 16; ++r2) O[r2] *= corr;
            // pack P^T into B-fragments via permlane32_swap (T12)
            uint a0 = pk2(S[0], S[1]), a1 = pk2(S[2], S[3]);
            uint b0 = pk2(S[4], S[5]), b1 = pk2(S[6], S[7]);
            uint a2 = pk2(S[8], S[9]), a3 = pk2(S[10], S[11]);
            uint b2w = pk2(S[12], S[13]), b3 = pk2(S[14], S[15]);
            i32x2v r01 = __builtin_amdgcn_permlane32_swap((int)a0, (int)b0, false, false);
            i32x2v r11 = __builtin_amdgcn_permlane32_swap((int)a1, (int)b1, false, false);
            i32x2v r21 = __builtin_amdgcn_permlane32_swap((int)a2, (int)b2w, false, false);
            i32x2v r31 = __builtin_amdgcn_permlane32_swap((int)a3, (int)b3, false, false);
            uint4 pf1u = {(uint)r01[0], (uint)r11[0], (uint)r01[1], (uint)r11[1]};
            uint4 pf2u = {(uint)r21[0], (uint)r31[0], (uint)r21[1], (uint)r31[1]};
            s16x8 va = *reinterpret_cast<const s16x8*>(&V_sm[lq][kt * 32 + hi * 8]);
            s16x8 vb = *reinterpret_cast<const s16x8*>(&V_sm[lq][kt * 32 + 16 + hi * 8]);
            O = __builtin_amdgcn_mfma_f32_32x32x16_bf16(va, __builtin_bit_cast(s16x8, pf1u), O, 0, 0, 0);
            O = __builtin_amdgcn_mfma_f32_32x32x16_bf16(vb, __builtin_bit_cast(s16x8, pf2u), O, 0, 0, 0);
        }
        float inv = 1.f / lsum;
        if (qok) {
            ushort* op = og + (rowbase + qv) * 128 + head * 32;
            #pragma unroll
            for (int g4 = 0; g4 < 4; ++g4) {
                int dbase = g4 * 8 + hi * 4;
                uint w0 = pk2(O[g4 * 4 + 0] * inv, O[g4 * 4 + 1] * inv);
                uint w1 = pk2(O[g4 * 4 + 2] * inv, O[g4 * 4 + 3] * inv);
                uint2 st = {w0, w1};
                *reinterpret_cast<uint2*>(op + dbase) = st;
            }
        }
    }
}

// ---------------- final: out[b][c][n] = (o @ wo)[n][c] + bo[c] + h[b][n][c] ------------------
__global__ __launch_bounds__(256) void kFinal(const ushort* __restrict__ ob, const float* __restrict__ wo,
                                              const float* __restrict__ bo, const float* __restrict__ h,
                                              float* __restrict__ out) {
    __shared__ float o_sm[64][16];
    __shared__ float w_sm2[16][128];
    __shared__ float tr[128][65];
    size_t p0 = (size_t)blockIdx.x * 64;
    int tid = threadIdx.x;
    int tc = tid & 31, tp = tid >> 5;
    float acc[8][4];
    #pragma unroll
    for (int i = 0; i < 8; ++i)
        #pragma unroll
        for (int j = 0; j < 4; ++j) acc[i][j] = 0.f;
    for (int c0 = 0; c0 < 128; c0 += 16) {
        for (int i = tid; i < 1024; i += 256) {
            int pp = i >> 4, cc = i & 15;
            size_t p = p0 + pp;
            o_sm[pp][cc] = (p < PTOT) ? b2f(ob[(p << 7) + c0 + cc]) : 0.f;
        }
        for (int i = tid; i < 2048; i += 256) {
            int r = i >> 7, cc = i & 127;
            w_sm2[r][cc] = wo[(size_t)(c0 + r) * 128 + cc];
        }
        __syncthreads();
        #pragma unroll
        for (int r = 0; r < 16; ++r) {
            float bv[4];
            #pragma unroll
            for (int j = 0; j < 4; ++j) bv[j] = w_sm2[r][tc * 4 + j];
            #pragma unroll
            for (int i = 0; i < 8; ++i) {
                float av = o_sm[tp * 8 + i][r];
                #pragma unroll
                for (int j = 0; j < 4; ++j) acc[i][j] += av * bv[j];
            }
        }
        __syncthreads();
    }
    #pragma unroll
    for (int i = 0; i < 8; ++i) {
        size_t p = p0 + tp * 8 + i;
        if (p < PTOT) {
            #pragma unroll
            for (int j = 0; j < 4; ++j) {
                int c = tc * 4 + j;
                tr[c][tp * 8 + i] = acc[i][j] + bo[c] + h[(p << 7) + c];
            }
        } else {
            #pragma unroll
            for (int j = 0; j < 4; ++j) tr[tc * 4 + j][tp * 8 + i] = 0.f;
        }
    }
    __syncthreads();
    for (int pass = 0; pass < 32; ++pass) {
        int idx = pass * 256 + tid;
        int row = idx >> 6, pc = idx & 63;
        size_t p = p0 + pc;
        if (p < PTOT) {
            int b = p >= (size_t)NOUT;
            size_t n = p - (size_t)b * NOUT;
            out[((size_t)(b * 128 + row)) * NOUT + n] = tr[row][pc];
        }
    }
}

extern "C" void kernel_launch(void* const* d_in, const int* in_sizes, int n_in,
                              void* d_out, int out_size, void* d_ws, size_t ws_size,
                              hipStream_t stream) {
    const float* x    = (const float*)d_in[0];
    const float* skip = (const float*)d_in[1];
    const float* wd   = (const float*)d_in[2];
    const float* bd   = (const float*)d_in[3];
    const float* psi  = (const float*)d_in[4];
    const float* quad = (const float*)d_in[5];
    const float* g1   = (const float*)d_in[6];
    const float* b1   = (const float*)d_in[7];
    const float* g2   = (const float*)d_in[8];
    const float* b2   = (const float*)d_in[9];
    const float* wqkv = (const float*)d_in[10];
    const float* bqkv = (const float*)d_in[11];
    const float* wo   = (const float*)d_in[12];
    const float* bo   = (const float*)d_in[13];
    const int* row    = (const int*)d_in[14];
    const int* col    = (const int*)d_in[15];
    const int* ker    = (const int*)d_in[16];
    float* ws = (float*)d_ws;
    float* xw = ws;                       // phase 1
    float* h  = ws + OFF_H;
    float* s1 = ws + OFF_S1;
    float* s2 = ws + OFF_S2;
    float* wt = ws + OFF_WT;
    ushort* qb  = (ushort*)(ws + OFF_Q);  // phase 2 (overlays xw); o aliases qb
    ushort* kb  = (ushort*)(ws + OFF_K);
    ushort* vtb = (ushort*)(ws + OFF_VT);
    float* out = (float*)d_out;

    hipMemsetAsync(h, 0, ((size_t)B_ * NOUT * CTOT + 64) * sizeof(float), stream);

    kT<<<288, 256, 0, stream>>>(wd, wt);
    kA<<<dim3(128, KK, B_), 256, 0, stream>>>(x, wt, quad, xw);
    kScatter<<<dim3(NNZ_ / 32, B_), 256, 0, stream>>>(xw, psi, row, col, ker, h);
    kSkip<<<dim3((NOUT + 31) / 32, 2, B_), dim3(32, 8), 0, stream>>>(skip, h);
    kStats1<<<dim3(64, 16), 256, 0, stream>>>(h, bd, s1);
    kApply1<<<(int)(((size_t)B_ * NOUT * 16 + 255) / 256), 256, 0, stream>>>(h, bd, g1, b1, s1);
    kStats2<<<dim3(64, 16), 256, 0, stream>>>(h, s2);
    kQKV<<<dim3((int)((PTOT + 63) / 64), 3), 256, 0, stream>>>(h, wqkv, bqkv, g2, b2, s2, qb, kb, vtb);
    kAttn<<<dim3(NH, HOUT, B_), 384, 0, stream>>>(qb, kb, vtb, qb /*o aliases q*/);
    kFinal<<<(int)((PTOT + 63) / 64), 256, 0, stream>>>(qb, wo, bo, h, out);
}

// Round 3
// 649.142 us; speedup vs baseline: 3.7338x; 1.1840x over previous
//
#include <hip/hip_runtime.h>
#include <hip/hip_bf16.h>

#define B_ 2
#define CIN 128
#define HIN 91
#define WIN 180
#define NIN (HIN*WIN)         // 16380
#define COUT_ 64
#define HOUT 181
#define WOUT 360
#define NOUT (HOUT*WOUT)      // 65160
#define KK 9
#define NNZ_ (NOUT*8)         // 521280
#define CTOT 128
#define NH 4
#define HD 32
#define EPS_ 1e-5f
#define PTOT ((size_t)B_*NOUT)   // 130320
#define BCAP 40                  // bucket capacity (Poisson(8) tail: P(>=40) ~ 1e-15/bin)

typedef short s16x8 __attribute__((ext_vector_type(8)));
typedef float f32x4v __attribute__((ext_vector_type(4)));
typedef float f32x16v __attribute__((ext_vector_type(16)));
typedef int i32x2v __attribute__((ext_vector_type(2)));

// workspace layout (float offsets)
// phase 1: xw [B][K][NIN][64] f32 occupies [0, 18869760)
// phase 2 (xw dead after gather): q bf16 + k bf16 overlay the xw region; o (bf16) aliases q.
#define OFF_Q  ((size_t)0)
#define OFF_K  ((size_t)8340480)
#define OFF_H  ((size_t)18869760)
#define OFF_S1 (OFF_H + (size_t)B_*NOUT*CTOT)        // 35550720
#define OFF_S2 (OFF_S1 + 32)
#define OFF_WT (OFF_S2 + 32)                         // 73728 floats
#define OFF_VT (OFF_WT + (size_t)KK*CIN*COUT_)       // 35624512, vt bf16 [B*128][NOUT]
// cnt+buckets alias the vt region (vt is dead until kQKV; buckets die after kGather)
#define OFF_CNT OFF_VT                               // 65536 ints
#define OFF_CSR (OFF_VT + 65536)                     // NOUT*BCAP uint2 = 5212800 float-slots

__device__ inline ushort f2b(float x) { return __bfloat16_as_ushort(__float2bfloat16(x)); }
__device__ inline float b2f(ushort u) { return __bfloat162float(__ushort_as_bfloat16(u)); }
__device__ inline uint pk2(float lo, float hi) {
    return (uint)f2b(lo) | ((uint)f2b(hi) << 16);
}

// ---------------- w_disco transpose: wt[k][cin][cout] = wd[cout][cin][k] ----------------
__global__ __launch_bounds__(256) void kT(const float* __restrict__ wd, float* __restrict__ wt) {
    int idx = blockIdx.x * 256 + threadIdx.x;
    if (idx >= KK * CIN * COUT_) return;
    int cout = idx & 63;
    int rest = idx >> 6;
    int cin = rest & 127;
    int k = rest >> 7;
    wt[idx] = wd[((size_t)cout * CIN + cin) * KK + k];
}

// ---------------- xw[b][k][n][cout] = quad[n/WIN] * sum_cin x[b][cin][n] * wt[k][cin][cout] ----
__global__ __launch_bounds__(256) void kA(const float* __restrict__ x, const float* __restrict__ wt,
                                          const float* __restrict__ quad, float* __restrict__ xw) {
    __shared__ float As[8][128];
    __shared__ float Bs[8][64];
    int n0 = blockIdx.x * 128;
    int k = blockIdx.y;
    int b = blockIdx.z;
    int tid = threadIdx.x;
    int tc = tid & 15;
    int tp = tid >> 4;
    float acc[8][4];
    #pragma unroll
    for (int i = 0; i < 8; ++i)
        #pragma unroll
        for (int j = 0; j < 4; ++j) acc[i][j] = 0.f;
    const float* xb = x + (size_t)b * CIN * NIN;
    const float* wk = wt + (size_t)k * CIN * COUT_;
    for (int c0 = 0; c0 < CIN; c0 += 8) {
        for (int i = tid; i < 1024; i += 256) {
            int r = i >> 7, nn = i & 127;
            int n = n0 + nn;
            As[r][nn] = (n < NIN) ? xb[(size_t)(c0 + r) * NIN + n] : 0.f;
        }
        for (int i = tid; i < 512; i += 256) {
            int r = i >> 6, cc = i & 63;
            Bs[r][cc] = wk[(size_t)(c0 + r) * COUT_ + cc];
        }
        __syncthreads();
        #pragma unroll
        for (int r = 0; r < 8; ++r) {
            float bv[4];
            #pragma unroll
            for (int j = 0; j < 4; ++j) bv[j] = Bs[r][tc * 4 + j];
            #pragma unroll
            for (int i = 0; i < 8; ++i) {
                float av = As[r][tp * 8 + i];
                #pragma unroll
                for (int j = 0; j < 4; ++j) acc[i][j] += av * bv[j];
            }
        }
        __syncthreads();
    }
    #pragma unroll
    for (int i = 0; i < 8; ++i) {
        int n = n0 + tp * 8 + i;
        if (n >= NIN) continue;
        float qd = quad[n / WIN];
        float* dst = xw + (((size_t)(b * KK + k) * NIN + n) << 6) + tc * 4;
        #pragma unroll
        for (int j = 0; j < 4; ++j) dst[j] = acc[i][j] * qd;
    }
}

// ---------------- kFill: bucket entries by output row ----------------------------------------
__global__ __launch_bounds__(256) void kFill(const int* __restrict__ row, const int* __restrict__ col,
                                             const int* __restrict__ ker, const float* __restrict__ psi,
                                             int* __restrict__ cnt, uint2* __restrict__ csr) {
    int e = blockIdx.x * 256 + threadIdx.x;
    if (e >= NNZ_) return;
    int r = row[e];
    int pos = atomicAdd(&cnt[r], 1);
    if (pos < BCAP) {
        uint2 pl;
        pl.x = (uint)col[e] | ((uint)ker[e] << 20);
        pl.y = __float_as_uint(psi[e]);
        csr[(size_t)r * BCAP + pos] = pl;
    }
}

// ---------------- kGather: h[b][r][cout] = sum_bucket psi * xw[b][ker][col][cout] ------------
__global__ __launch_bounds__(256) void kGather(const float* __restrict__ xw, const int* __restrict__ cnt,
                                               const uint2* __restrict__ csr, float* __restrict__ h) {
    int lane = threadIdx.x & 63;
    int wv = threadIdx.x >> 6;
    int r = blockIdx.x * 4 + wv;
    if (r >= NOUT) return;
    int n = min(cnt[r], BCAP);
    float a0 = 0.f, a1 = 0.f;
    const uint2* bucket = csr + (size_t)r * BCAP;
    const size_t bstride = ((size_t)KK * NIN) << 6;
    for (int i = 0; i < n; ++i) {
        uint2 pl = bucket[i];
        int c = pl.x & 0xFFFFF;
        int kk = pl.x >> 20;
        float p = __uint_as_float(pl.y);
        size_t base = (((size_t)kk * NIN + c) << 6) + lane;
        a0 += p * xw[base];
        a1 += p * xw[base + bstride];
    }
    h[(((size_t)r) << 7) + lane] = a0;
    h[(((size_t)NOUT + r) << 7) + lane] = a1;
}

// ---------------- skip transpose into h channels 64..127 -------------------------------------
__global__ __launch_bounds__(256) void kSkip(const float* __restrict__ skip, float* __restrict__ h) {
    __shared__ float tile[32][33];
    int n0 = blockIdx.x * 32, c0 = blockIdx.y * 32, b = blockIdx.z;
    int tx = threadIdx.x, ty = threadIdx.y;
    #pragma unroll
    for (int j = 0; j < 4; ++j) {
        int c = c0 + ty + j * 8, n = n0 + tx;
        if (n < NOUT) tile[ty + j * 8][tx] = skip[((size_t)b * 64 + c) * NOUT + n];
    }
    __syncthreads();
    #pragma unroll
    for (int j = 0; j < 4; ++j) {
        int n = n0 + ty + j * 8, c = c0 + tx;
        if (n < NOUT) h[(((size_t)b * NOUT + n) << 7) + 64 + c] = tile[tx][ty + j * 8];
    }
}

// ---------------- GN1 stats ------------------------------------------------------------------
__global__ __launch_bounds__(256) void kStats1(const float* __restrict__ h, const float* __restrict__ bd,
                                               float* __restrict__ s1) {
    int bg = blockIdx.y;
    int b = bg >> 3, g = bg & 7;
    float s = 0.f, sq = 0.f;
    const int total = NOUT * 2;
    for (int idx = blockIdx.x * 256 + threadIdx.x; idx < total; idx += 64 * 256) {
        int n = idx >> 1, c4 = idx & 1;
        const float4 v = *reinterpret_cast<const float4*>(h + (((size_t)b * NOUT + n) << 7) + g * 8 + c4 * 4);
        const float4 b4 = *reinterpret_cast<const float4*>(bd + g * 8 + c4 * 4);
        float a0 = v.x + b4.x, a1 = v.y + b4.y, a2 = v.z + b4.z, a3 = v.w + b4.w;
        s += a0 + a1 + a2 + a3;
        sq += a0 * a0 + a1 * a1 + a2 * a2 + a3 * a3;
    }
    for (int o = 32; o; o >>= 1) { s += __shfl_down(s, o); sq += __shfl_down(sq, o); }
    __shared__ float red[8];
    int wv = threadIdx.x >> 6;
    if ((threadIdx.x & 63) == 0) { red[wv * 2] = s; red[wv * 2 + 1] = sq; }
    __syncthreads();
    if (threadIdx.x == 0) {
        float S = 0.f, SQ = 0.f;
        for (int w = 0; w < 4; ++w) { S += red[w * 2]; SQ += red[w * 2 + 1]; }
        atomicAdd(&s1[bg * 2], S);
        atomicAdd(&s1[bg * 2 + 1], SQ);
    }
}

// ---------------- apply GN1 + exact GELU -----------------------------------------------------
__global__ __launch_bounds__(256) void kApply1(float* __restrict__ h, const float* __restrict__ bd,
                                               const float* __restrict__ g1, const float* __restrict__ b1,
                                               const float* __restrict__ s1) {
    size_t idx = (size_t)blockIdx.x * 256 + threadIdx.x;
    if (idx >= (size_t)B_ * NOUT * 16) return;
    int c4 = (int)(idx & 15);
    size_t pn = idx >> 4;
    int b = pn >= (size_t)NOUT;
    int g = c4 >> 1;
    const float invc = 1.0f / (8.0f * NOUT);
    float mu = s1[(b * 8 + g) * 2] * invc;
    float ex2 = s1[(b * 8 + g) * 2 + 1] * invc;
    float rstd = rsqrtf(ex2 - mu * mu + EPS_);
    float* p = h + (pn << 7) + (c4 << 2);
    float4 v = *reinterpret_cast<float4*>(p);
    float r[4] = {v.x, v.y, v.z, v.w};
    #pragma unroll
    for (int j = 0; j < 4; ++j) {
        int c = (c4 << 2) + j;
        float a = r[j] + bd[c];
        float t = (a - mu) * rstd * g1[c] + b1[c];
        r[j] = t * 0.5f * (1.0f + erff(t * 0.70710678118654752f));
    }
    v.x = r[0]; v.y = r[1]; v.z = r[2]; v.w = r[3];
    *reinterpret_cast<float4*>(p) = v;
}

// ---------------- GN2 stats ------------------------------------------------------------------
__global__ __launch_bounds__(256) void kStats2(const float* __restrict__ h, float* __restrict__ s2) {
    int bg = blockIdx.y;
    int b = bg >> 3, g = bg & 7;
    float s = 0.f, sq = 0.f;
    const int total = NOUT * 4;
    for (int idx = blockIdx.x * 256 + threadIdx.x; idx < total; idx += 64 * 256) {
        int n = idx >> 2, c4 = idx & 3;
        const float4 v = *reinterpret_cast<const float4*>(h + (((size_t)b * NOUT + n) << 7) + g * 16 + c4 * 4);
        s += v.x + v.y + v.z + v.w;
        sq += v.x * v.x + v.y * v.y + v.z * v.z + v.w * v.w;
    }
    for (int o = 32; o; o >>= 1) { s += __shfl_down(s, o); sq += __shfl_down(sq, o); }
    __shared__ float red[8];
    int wv = threadIdx.x >> 6;
    if ((threadIdx.x & 63) == 0) { red[wv * 2] = s; red[wv * 2 + 1] = sq; }
    __syncthreads();
    if (threadIdx.x == 0) {
        float S = 0.f, SQ = 0.f;
        for (int w = 0; w < 4; ++w) { S += red[w * 2]; SQ += red[w * 2 + 1]; }
        atomicAdd(&s2[bg * 2], S);
        atomicAdd(&s2[bg * 2 + 1], SQ);
    }
}

// ---------------- kQKV: t = GN2(h); qkv = t @ wqkv + bqkv via MFMA ---------------------------
__global__ __launch_bounds__(256) void kQKV(const float* __restrict__ h, const float* __restrict__ wqkv,
                                            const float* __restrict__ bqkv, const float* __restrict__ g2,
                                            const float* __restrict__ b2, const float* __restrict__ s2,
                                            ushort* __restrict__ qg, ushort* __restrict__ kg,
                                            ushort* __restrict__ vtg) {
    __shared__ ushort As[64][136];
    __shared__ ushort Bs[128][136];
    __shared__ float muT[16], rsT[16];
    __shared__ float g2T[128], b2T[128];
    int tid = threadIdx.x;
    size_t r0 = (size_t)blockIdx.x * 64;
    int n0 = blockIdx.y * 128;
    const float invc2 = 1.0f / (16.0f * NOUT);
    if (tid < 16) {
        float mu = s2[tid * 2] * invc2;
        float ex2 = s2[tid * 2 + 1] * invc2;
        muT[tid] = mu;
        rsT[tid] = rsqrtf(ex2 - mu * mu + EPS_);
    }
    if (tid < 128) { g2T[tid] = g2[tid]; b2T[tid] = b2[tid]; }
    __syncthreads();
    for (int i = tid; i < 64 * 32; i += 256) {
        int rl = i >> 5, c4 = (i & 31) * 4;
        size_t rg = r0 + rl;
        uint w0 = 0, w1 = 0;
        if (rg < PTOT) {
            int bg8 = (rg >= (size_t)NOUT) ? 8 : 0;
            int g = bg8 + (c4 >> 4);
            float mu = muT[g], rs = rsT[g];
            float4 v = *reinterpret_cast<const float4*>(h + (rg << 7) + c4);
            float t0 = (v.x - mu) * rs * g2T[c4] + b2T[c4];
            float t1 = (v.y - mu) * rs * g2T[c4 + 1] + b2T[c4 + 1];
            float t2 = (v.z - mu) * rs * g2T[c4 + 2] + b2T[c4 + 2];
            float t3 = (v.w - mu) * rs * g2T[c4 + 3] + b2T[c4 + 3];
            w0 = pk2(t0, t1); w1 = pk2(t2, t3);
        }
        *reinterpret_cast<uint*>(&As[rl][c4]) = w0;
        *reinterpret_cast<uint*>(&As[rl][c4 + 2]) = w1;
    }
    for (int i = tid; i < 128 * 32; i += 256) {
        int kk = i >> 5, n4 = (i & 31) * 4;
        float4 v = *reinterpret_cast<const float4*>(wqkv + (size_t)kk * 384 + n0 + n4);
        Bs[n4][kk] = f2b(v.x); Bs[n4 + 1][kk] = f2b(v.y);
        Bs[n4 + 2][kk] = f2b(v.z); Bs[n4 + 3][kk] = f2b(v.w);
    }
    __syncthreads();
    int w = tid >> 6, lane = tid & 63;
    int l16 = lane & 15, kh = lane >> 4;
    f32x4v acc[8];
    #pragma unroll
    for (int nf = 0; nf < 8; ++nf) { acc[nf][0] = 0; acc[nf][1] = 0; acc[nf][2] = 0; acc[nf][3] = 0; }
    #pragma unroll
    for (int ks = 0; ks < 4; ++ks) {
        int kk0 = ks * 32 + kh * 8;
        s16x8 af = *reinterpret_cast<const s16x8*>(&As[w * 16 + l16][kk0]);
        #pragma unroll
        for (int nf = 0; nf < 8; ++nf) {
            s16x8 bf = *reinterpret_cast<const s16x8*>(&Bs[nf * 16 + l16][kk0]);
            acc[nf] = __builtin_amdgcn_mfma_f32_16x16x32_bf16(af, bf, acc[nf], 0, 0, 0);
        }
    }
    __syncthreads();
    const float scale = (n0 == 0) ? 0.17677669529663688f : 1.0f;
    #pragma unroll
    for (int nf = 0; nf < 8; ++nf) {
        int cc = nf * 16 + l16;
        float bias = bqkv[n0 + cc];
        #pragma unroll
        for (int j = 0; j < 4; ++j) {
            int rl = w * 16 + kh * 4 + j;
            As[rl][cc] = f2b((acc[nf][j] + bias) * scale);
        }
    }
    __syncthreads();
    if (n0 < 256) {
        ushort* dst = (n0 == 0) ? qg : kg;
        for (int i = tid; i < 64 * 64; i += 256) {
            int rl = i >> 6, dc = i & 63;
            size_t rg = r0 + rl;
            if (rg < PTOT)
                reinterpret_cast<uint*>(dst)[(rg << 6) + dc] =
                    reinterpret_cast<const uint*>(&As[rl][0])[dc];
        }
    } else {
        for (int i = tid; i < 128 * 64; i += 256) {
            int d128 = i >> 6, rl = i & 63;
            size_t rg = r0 + rl;
            if (rg < PTOT) {
                int b = rg >= (size_t)NOUT;
                size_t n = rg - (size_t)b * NOUT;
                vtg[((size_t)(b * 128 + d128)) * NOUT + n] = As[rl][d128];
            }
        }
    }
}

// ---------------- kAttn: flash attention per (head, ring, b) via MFMA 32x32x16 ---------------
__global__ __launch_bounds__(384) void kAttn(const ushort* __restrict__ qg, const ushort* __restrict__ kg,
                                             const ushort* __restrict__ vtg, ushort* __restrict__ og) {
    __shared__ ushort K_sm[384][40];
    __shared__ ushort V_sm[32][392];
    int head = blockIdx.x, ring = blockIdx.y, b = blockIdx.z;
    int tid = threadIdx.x;
    size_t rowbase = (size_t)b * NOUT + (size_t)ring * 360;
    for (int i = tid; i < 1536; i += 384) {
        int r = i >> 2, c = (i & 3) * 8;
        uint4 val = {0, 0, 0, 0};
        if (r < 360) val = *reinterpret_cast<const uint4*>(kg + (rowbase + r) * 128 + head * 32 + c);
        *reinterpret_cast<uint4*>(&K_sm[r][c]) = val;
    }
    {
        int d = tid / 12, j = tid % 12;
        const ushort* vp = vtg + ((size_t)(b * 128 + head * 32 + d)) * NOUT + (size_t)ring * 360;
        for (int c8 = j; c8 < 49; c8 += 12) {
            uint4 val = {0, 0, 0, 0};
            if (c8 < 45) val = *reinterpret_cast<const uint4*>(vp + c8 * 8);
            *reinterpret_cast<uint4*>(&V_sm[d][c8 * 8]) = val;
        }
    }
    __syncthreads();
    int wv = tid >> 6, lane = tid & 63;
    int lq = lane & 31, hi = lane >> 5;
    for (int qi = 0; qi < 2; ++qi) {
        int qt = wv + qi * 6;
        int qv = qt * 32 + lq;
        bool qok = qv < 360;
        uint4 qf1 = {0, 0, 0, 0}, qf2 = {0, 0, 0, 0};
        if (qok) {
            const ushort* qp = qg + (rowbase + qv) * 128 + head * 32;
            qf1 = *reinterpret_cast<const uint4*>(qp + hi * 8);
            qf2 = *reinterpret_cast<const uint4*>(qp + 16 + hi * 8);
        }
        s16x8 qa = __builtin_bit_cast(s16x8, qf1);
        s16x8 qb = __builtin_bit_cast(s16x8, qf2);
        f32x16v O;
        #pragma unroll
        for (int r2 = 0; r2 < 16; ++r2) O[r2] = 0.f;
        float m = -INFINITY, lsum = 0.f;
        for (int kt = 0; kt < 12; ++kt) {
            s16x8 ka = *reinterpret_cast<const s16x8*>(&K_sm[kt * 32 + lq][hi * 8]);
            s16x8 kb = *reinterpret_cast<const s16x8*>(&K_sm[kt * 32 + lq][16 + hi * 8]);
            f32x16v S;
            #pragma unroll
            for (int r2 = 0; r2 < 16; ++r2) S[r2] = 0.f;
            S = __builtin_amdgcn_mfma_f32_32x32x16_bf16(ka, qa, S, 0, 0, 0);
            S = __builtin_amdgcn_mfma_f32_32x32x16_bf16(kb, qb, S, 0, 0, 0);
            if (kt == 11) {
                #pragma unroll
                for (int r2 = 4; r2 < 16; ++r2) S[r2] = -1e30f;
            }
            float tm = S[0];
            #pragma unroll
            for (int r2 = 1; r2 < 16; ++r2) tm = fmaxf(tm, S[r2]);
            i32x2v sw = __builtin_amdgcn_permlane32_swap(__float_as_int(tm), __float_as_int(tm), false, false);
            tm = fmaxf(__int_as_float(sw[0]), __int_as_float(sw[1]));
            float mn = fmaxf(m, tm);
            float corr = __expf(m - mn);
            float ps = 0.f;
            #pragma unroll
            for (int r2 = 0; r2 < 16; ++r2) { S[r2] = __expf(S[r2] - mn); ps += S[r2]; }
            sw = __builtin_amdgcn_permlane32_swap(__float_as_int(ps), __float_as_int(ps), false, false);
            ps = __int_as_float(sw[0]) + __int_as_float(sw[1]);
            lsum = lsum * corr + ps;
            m = mn;
            #pragma unroll
            for (int r2 = 0; r2 < 16; ++r2) O[r2] *= corr;
            uint a0 = pk2(S[0], S[1]), a1 = pk2(S[2], S[3]);
            uint b0 = pk2(S[4], S[5]), b1 = pk2(S[6], S[7]);
            uint a2 = pk2(S[8], S[9]), a3 = pk2(S[10], S[11]);
            uint b2w = pk2(S[12], S[13]), b3 = pk2(S[14], S[15]);
            i32x2v r01 = __builtin_amdgcn_permlane32_swap((int)a0, (int)b0, false, false);
            i32x2v r11 = __builtin_amdgcn_permlane32_swap((int)a1, (int)b1, false, false);
            i32x2v r21 = __builtin_amdgcn_permlane32_swap((int)a2, (int)b2w, false, false);
            i32x2v r31 = __builtin_amdgcn_permlane32_swap((int)a3, (int)b3, false, false);
            uint4 pf1u = {(uint)r01[0], (uint)r11[0], (uint)r01[1], (uint)r11[1]};
            uint4 pf2u = {(uint)r21[0], (uint)r31[0], (uint)r21[1], (uint)r31[1]};
            s16x8 va = *reinterpret_cast<const s16x8*>(&V_sm[lq][kt * 32 + hi * 8]);
            s16x8 vb = *reinterpret_cast<const s16x8*>(&V_sm[lq][kt * 32 + 16 + hi * 8]);
            O = __builtin_amdgcn_mfma_f32_32x32x16_bf16(va, __builtin_bit_cast(s16x8, pf1u), O, 0, 0, 0);
            O = __builtin_amdgcn_mfma_f32_32x32x16_bf16(vb, __builtin_bit_cast(s16x8, pf2u), O, 0, 0, 0);
        }
        float inv = 1.f / lsum;
        if (qok) {
            ushort* op = og + (rowbase + qv) * 128 + head * 32;
            #pragma unroll
            for (int g4 = 0; g4 < 4; ++g4) {
                int dbase = g4 * 8 + hi * 4;
                uint w0 = pk2(O[g4 * 4 + 0] * inv, O[g4 * 4 + 1] * inv);
                uint w1 = pk2(O[g4 * 4 + 2] * inv, O[g4 * 4 + 3] * inv);
                uint2 st = {w0, w1};
                *reinterpret_cast<uint2*>(op + dbase) = st;
            }
        }
    }
}

// ---------------- final: out[b][c][n] = (o @ wo)[n][c] + bo[c] + h[b][n][c] ------------------
__global__ __launch_bounds__(256) void kFinal(const ushort* __restrict__ ob, const float* __restrict__ wo,
                                              const float* __restrict__ bo, const float* __restrict__ h,
                                              float* __restrict__ out) {
    __shared__ float o_sm[64][16];
    __shared__ float w_sm2[16][128];
    __shared__ float tr[128][65];
    size_t p0 = (size_t)blockIdx.x * 64;
    int tid = threadIdx.x;
    int tc = tid & 31, tp = tid >> 5;
    float acc[8][4];
    #pragma unroll
    for (int i = 0; i < 8; ++i)
        #pragma unroll
        for (int j = 0; j < 4; ++j) acc[i][j] = 0.f;
    for (int c0 = 0; c0 < 128; c0 += 16) {
        for (int i = tid; i < 1024; i += 256) {
            int pp = i >> 4, cc = i & 15;
            size_t p = p0 + pp;
            o_sm[pp][cc] = (p < PTOT) ? b2f(ob[(p << 7) + c0 + cc]) : 0.f;
        }
        for (int i = tid; i < 2048; i += 256) {
            int r = i >> 7, cc = i & 127;
            w_sm2[r][cc] = wo[(size_t)(c0 + r) * 128 + cc];
        }
        __syncthreads();
        #pragma unroll
        for (int r = 0; r < 16; ++r) {
            float bv[4];
            #pragma unroll
            for (int j = 0; j < 4; ++j) bv[j] = w_sm2[r][tc * 4 + j];
            #pragma unroll
            for (int i = 0; i < 8; ++i) {
                float av = o_sm[tp * 8 + i][r];
                #pragma unroll
                for (int j = 0; j < 4; ++j) acc[i][j] += av * bv[j];
            }
        }
        __syncthreads();
    }
    #pragma unroll
    for (int i = 0; i < 8; ++i) {
        size_t p = p0 + tp * 8 + i;
        if (p < PTOT) {
            #pragma unroll
            for (int j = 0; j < 4; ++j) {
                int c = tc * 4 + j;
                tr[c][tp * 8 + i] = acc[i][j] + bo[c] + h[(p << 7) + c];
            }
        } else {
            #pragma unroll
            for (int j = 0; j < 4; ++j) tr[tc * 4 + j][tp * 8 + i] = 0.f;
        }
    }
    __syncthreads();
    for (int pass = 0; pass < 32; ++pass) {
        int idx = pass * 256 + tid;
        int row = idx >> 6, pc = idx & 63;
        size_t p = p0 + pc;
        if (p < PTOT) {
            int b = p >= (size_t)NOUT;
            size_t n = p - (size_t)b * NOUT;
            out[((size_t)(b * 128 + row)) * NOUT + n] = tr[row][pc];
        }
    }
}

extern "C" void kernel_launch(void* const* d_in, const int* in_sizes, int n_in,
                              void* d_out, int out_size, void* d_ws, size_t ws_size,
                              hipStream_t stream) {
    const float* x    = (const float*)d_in[0];
    const float* skip = (const float*)d_in[1];
    const float* wd   = (const float*)d_in[2];
    const float* bd   = (const float*)d_in[3];
    const float* psi  = (const float*)d_in[4];
    const float* quad = (const float*)d_in[5];
    const float* g1   = (const float*)d_in[6];
    const float* b1   = (const float*)d_in[7];
    const float* g2   = (const float*)d_in[8];
    const float* b2   = (const float*)d_in[9];
    const float* wqkv = (const float*)d_in[10];
    const float* bqkv = (const float*)d_in[11];
    const float* wo   = (const float*)d_in[12];
    const float* bo   = (const float*)d_in[13];
    const int* row    = (const int*)d_in[14];
    const int* col    = (const int*)d_in[15];
    const int* ker    = (const int*)d_in[16];
    float* ws = (float*)d_ws;
    float* xw = ws;                       // phase 1
    float* h  = ws + OFF_H;
    float* s1 = ws + OFF_S1;
    float* s2 = ws + OFF_S2;
    float* wt = ws + OFF_WT;
    int*   cnt = (int*)(ws + OFF_CNT);
    uint2* csr = (uint2*)(ws + OFF_CSR);
    ushort* qb  = (ushort*)(ws + OFF_Q);  // phase 2 (overlays xw); o aliases qb
    ushort* kb  = (ushort*)(ws + OFF_K);
    ushort* vtb = (ushort*)(ws + OFF_VT);
    float* out = (float*)d_out;

    hipMemsetAsync(s1, 0, 64 * sizeof(float), stream);          // s1 + s2
    hipMemsetAsync(cnt, 0, 65536 * sizeof(int), stream);        // bucket counters

    kT<<<288, 256, 0, stream>>>(wd, wt);
    kFill<<<(NNZ_ + 255) / 256, 256, 0, stream>>>(row, col, ker, psi, cnt, csr);
    kA<<<dim3(128, KK, B_), 256, 0, stream>>>(x, wt, quad, xw);
    kGather<<<(NOUT + 3) / 4, 256, 0, stream>>>(xw, cnt, csr, h);
    kSkip<<<dim3((NOUT + 31) / 32, 2, B_), dim3(32, 8), 0, stream>>>(skip, h);
    kStats1<<<dim3(64, 16), 256, 0, stream>>>(h, bd, s1);
    kApply1<<<(int)(((size_t)B_ * NOUT * 16 + 255) / 256), 256, 0, stream>>>(h, bd, g1, b1, s1);
    kStats2<<<dim3(64, 16), 256, 0, stream>>>(h, s2);
    kQKV<<<dim3((int)((PTOT + 63) / 64), 3), 256, 0, stream>>>(h, wqkv, bqkv, g2, b2, s2, qb, kb, vtb);
    kAttn<<<dim3(NH, HOUT, B_), 384, 0, stream>>>(qb, kb, vtb, qb /*o aliases q*/);
    kFinal<<<(int)((PTOT + 63) / 64), 256, 0, stream>>>(qb, wo, bo, h, out);
}